// Round 10
// baseline (315.837 us; speedup 1.0000x reference)
//
#include <hip/hip_runtime.h>
#include <hip/hip_fp16.h>
#include <cmath>

#define Tn 8192
#define Dn 512
#define Fn 2048
#define En 8

typedef _Float16 f16x8 __attribute__((ext_vector_type(8)));
typedef _Float16 f16x4 __attribute__((ext_vector_type(4)));
typedef float f32x4 __attribute__((ext_vector_type(4)));

#define MAXTILES 136    // ceil(Tn/64) + En

__device__ __forceinline__ void gload16(const void* g, void* l) {
    __builtin_amdgcn_global_load_lds(
        (const __attribute__((address_space(1))) unsigned int*)g,
        (__attribute__((address_space(3))) unsigned int*)l, 16, 0, 0);
}

// A&S 7.1.26 rational erf, |eps| <= 1.5e-7
__device__ __forceinline__ float fast_gelu(float v) {
    float z = fabsf(v) * 0.70710678118654752f;
    float t = 1.0f / fmaf(0.3275911f, z, 1.0f);
    float p = t * fmaf(t, fmaf(t, fmaf(t, fmaf(t, 1.061405429f, -1.453152027f),
                                       1.421413741f), -0.284496736f), 0.254829592f);
    float e = __expf(-z * z);
    float erfa = fmaf(-p, e, 1.0f);                 // erf(|z|)
    float phi = 0.5f + copysignf(0.5f * erfa, v);   // 0.5*(1+erf(v/sqrt2))
    return v * phi;
}

// ---------------- router: logits, softmax top-1, hist + x->fp16 cvt ----------------
__global__ __launch_bounds__(256) void router_kernel(
    const float* __restrict__ x, const float* __restrict__ Ws,
    const float* __restrict__ bs, _Float16* __restrict__ x16,
    int* __restrict__ route, float* __restrict__ scale,
    int* __restrict__ poslocal, int* __restrict__ blockCounts)
{
    __shared__ int hist[8];
    const int tid = threadIdx.x;
    if (tid < 8) hist[tid] = 0;
    __syncthreads();

    const int lane = tid & 63;
    const int w = tid >> 6;
    const int tokBase = blockIdx.x * 32 + w * 8;

    float wreg[8][8];
#pragma unroll
    for (int j = 0; j < 4; ++j) {
        const float4* p = reinterpret_cast<const float4*>(Ws + (4 * lane + j) * En);
        float4 a = p[0], b = p[1];
        wreg[j][0] = a.x; wreg[j][1] = a.y; wreg[j][2] = a.z; wreg[j][3] = a.w;
        wreg[j][4] = b.x; wreg[j][5] = b.y; wreg[j][6] = b.z; wreg[j][7] = b.w;
    }
#pragma unroll
    for (int j = 0; j < 4; ++j) {
        const float4* p = reinterpret_cast<const float4*>(Ws + (256 + 4 * lane + j) * En);
        float4 a = p[0], b = p[1];
        wreg[4 + j][0] = a.x; wreg[4 + j][1] = a.y; wreg[4 + j][2] = a.z; wreg[4 + j][3] = a.w;
        wreg[4 + j][4] = b.x; wreg[4 + j][5] = b.y; wreg[4 + j][6] = b.z; wreg[4 + j][7] = b.w;
    }
    float bsv[8];
#pragma unroll
    for (int e = 0; e < 8; ++e) bsv[e] = bs[e];

    for (int it = 0; it < 8; ++it) {
        int t = tokBase + it;
        const float4* xr = reinterpret_cast<const float4*>(x + (size_t)t * Dn);
        float4 v0 = xr[lane];
        float4 v1 = xr[64 + lane];
        f16x4 h0, h1;
        h0[0] = (_Float16)v0.x; h0[1] = (_Float16)v0.y; h0[2] = (_Float16)v0.z; h0[3] = (_Float16)v0.w;
        h1[0] = (_Float16)v1.x; h1[1] = (_Float16)v1.y; h1[2] = (_Float16)v1.z; h1[3] = (_Float16)v1.w;
        *reinterpret_cast<f16x4*>(x16 + (size_t)t * Dn + 4 * lane) = h0;
        *reinterpret_cast<f16x4*>(x16 + (size_t)t * Dn + 256 + 4 * lane) = h1;

        float xv[8] = {v0.x, v0.y, v0.z, v0.w, v1.x, v1.y, v1.z, v1.w};
        float part[8];
#pragma unroll
        for (int e = 0; e < 8; ++e) part[e] = 0.f;
#pragma unroll
        for (int j = 0; j < 8; ++j)
#pragma unroll
            for (int e = 0; e < 8; ++e) part[e] = fmaf(xv[j], wreg[j][e], part[e]);
#pragma unroll
        for (int s = 32; s > 0; s >>= 1) {
#pragma unroll
            for (int e = 0; e < 8; ++e) part[e] += __shfl_xor(part[e], s);
        }
        if (lane == 0) {
            float lg[8];
            lg[0] = part[0] + bsv[0];
            float m = lg[0]; int am = 0;
#pragma unroll
            for (int e = 1; e < 8; ++e) {
                lg[e] = part[e] + bsv[e];
                if (lg[e] > m) { m = lg[e]; am = e; }   // first-max tie rule
            }
            float sum = 0.f;
#pragma unroll
            for (int e = 0; e < 8; ++e) sum += expf(lg[e] - m);
            route[t] = am;
            scale[t] = 1.0f / sum;                 // top-1 softmax prob
            poslocal[t] = atomicAdd(&hist[am], 1); // LDS atomic: local rank
        }
    }
    __syncthreads();
    if (tid < 8) blockCounts[blockIdx.x * 8 + tid] = hist[tid];
}

// ---------------- plan: prefix sums (no atomics) + tile table ----------------
__global__ __launch_bounds__(256) void plan_kernel(
    const int* __restrict__ blockCounts,   // [256][8]
    int* __restrict__ base,                // [256][8] out
    int* __restrict__ nTiles, int* __restrict__ tileExpert,
    int* __restrict__ tileBase, int* __restrict__ tileEnd)
{
    __shared__ int cnt[256 * 8];
    __shared__ int groupSum[32 * 8];
    __shared__ int groupBase[32 * 8];
    __shared__ int totals[8];
    __shared__ int offsets_s[8];
    const int tid = threadIdx.x;
    for (int i = tid; i < 2048; i += 256) cnt[i] = blockCounts[i];
    __syncthreads();
    const int e = tid & 7, g = tid >> 3;
    {
        int s = 0;
#pragma unroll
        for (int b = g * 8; b < g * 8 + 8; ++b) s += cnt[b * 8 + e];
        groupSum[g * 8 + e] = s;
    }
    __syncthreads();
    if (tid < 8) {
        int run = 0;
        for (int gg = 0; gg < 32; ++gg) {
            groupBase[gg * 8 + tid] = run;
            run += groupSum[gg * 8 + tid];
        }
        totals[tid] = run;
    }
    __syncthreads();
    if (tid == 0) {
        int off = 0, nt = 0;
        for (int ee = 0; ee < En; ++ee) {
            offsets_s[ee] = off;
            int c = totals[ee];
            int tiles = (c + 63) / 64;
            for (int r = 0; r < tiles; ++r) {
                tileExpert[nt] = ee;
                tileBase[nt] = off + r * 64;
                tileEnd[nt] = off + c;
                ++nt;
            }
            off += c;
        }
        *nTiles = nt;
    }
    __syncthreads();
    {
        int run = offsets_s[e] + groupBase[g * 8 + e];
#pragma unroll
        for (int b = g * 8; b < g * 8 + 8; ++b) {
            base[b * 8 + e] = run;
            run += cnt[b * 8 + e];
        }
    }
}

// ---------------- scatter: pure writes, no atomics ----------------
__global__ __launch_bounds__(256) void scatter_kernel(
    const int* __restrict__ route, const int* __restrict__ poslocal,
    const int* __restrict__ base, int* __restrict__ order)
{
    int t = blockIdx.x * 256 + threadIdx.x;
    if (t >= Tn) return;
    int e = route[t];
    int rb = t >> 5;
    order[base[rb * 8 + e] + poslocal[t]] = t;
}

// ---------------- transpose + fp32->fp16 for W1, W2 ----------------
__global__ __launch_bounds__(256) void transpose_cvt_kernel(
    const float* __restrict__ W1, const float* __restrict__ W2,
    _Float16* __restrict__ W1T, _Float16* __restrict__ W2T)
{
    __shared__ float tile[64][65];
    int bx = blockIdx.x;
    const float* in; _Float16* outp; int R, C, tR, tC;
    if (bx < 2048) {            // W1[e]: [D][F] -> W1T[e]: [F][D]
        int e = bx >> 8, t = bx & 255;
        R = Dn; C = Fn; tR = t >> 5; tC = t & 31;
        in = W1 + (size_t)e * Dn * Fn;
        outp = W1T + (size_t)e * Dn * Fn;
    } else {                    // W2[e]: [F][D] -> W2T[e]: [D][F]
        int b2 = bx - 2048;
        int e = b2 >> 8, t = b2 & 255;
        R = Fn; C = Dn; tR = t >> 3; tC = t & 7;
        in = W2 + (size_t)e * Fn * Dn;
        outp = W2T + (size_t)e * Fn * Dn;
    }
    int r0 = tR * 64, c0 = tC * 64;
    int row = threadIdx.x >> 2, cq = threadIdx.x & 3;
#pragma unroll
    for (int i = 0; i < 4; ++i) {
        float4 v = *reinterpret_cast<const float4*>(in + (size_t)(r0 + row) * C + c0 + cq * 16 + i * 4);
        tile[row][cq * 16 + i * 4 + 0] = v.x;
        tile[row][cq * 16 + i * 4 + 1] = v.y;
        tile[row][cq * 16 + i * 4 + 2] = v.z;
        tile[row][cq * 16 + i * 4 + 3] = v.w;
    }
    __syncthreads();
    int col = threadIdx.x >> 2, rq = threadIdx.x & 3;
    f16x8 o0, o1;
#pragma unroll
    for (int i = 0; i < 8; ++i) o0[i] = (_Float16)tile[rq * 16 + i][col];
#pragma unroll
    for (int i = 0; i < 8; ++i) o1[i] = (_Float16)tile[rq * 16 + 8 + i][col];
    size_t base = (size_t)(c0 + col) * R + r0 + rq * 16;
    *reinterpret_cast<f16x8*>(outp + base) = o0;
    *reinterpret_cast<f16x8*>(outp + base + 8) = o1;
}

// ---------------- GEMM1: h = gelu(Xg @ W1 + b1) ----------------
// ONE WAVE per block, tile 64x64, BK=32, 8 KB LDS (chunk-major, conflict-free),
// R7 loop: STAGE -> vmcnt(0) -> ds_read frags -> lgkmcnt(0) -> STAGE(next) -> MFMA.
__global__ __launch_bounds__(64) void gemm1_kernel(
    const _Float16* __restrict__ x16, const _Float16* __restrict__ W1T,
    const float* __restrict__ b1, const int* __restrict__ order,
    const int* __restrict__ nTiles, const int* __restrict__ tileExpert,
    const int* __restrict__ tileBase, const int* __restrict__ tileEnd,
    _Float16* __restrict__ hbuf)
{
    __shared__ _Float16 As[64 * 32];   // chunk-major: As[c*64+r] holds A[r][c*8..c*8+7]
    __shared__ _Float16 Bs[64 * 32];
    const int bt = blockIdx.x;
    if (bt >= *nTiles) return;
    const int e = tileExpert[bt], rowBase = tileBase[bt], rowEnd = tileEnd[bt];
    const int nBase = blockIdx.y * 64;
    const int lane = threadIdx.x;

    // lane stages its OWN row (r = lane), chunks p=0..3
    const int tok = order[min(rowBase + lane, Tn - 1)];
    const _Float16* Asrc = x16 + (size_t)tok * Dn;
    const _Float16* Bsrc = W1T + (size_t)e * Dn * Fn + (size_t)(nBase + lane) * Dn;

#define STAGE1(kt) do {                                                  \
        _Pragma("unroll")                                                \
        for (int p = 0; p < 4; ++p) {                                    \
            gload16(Asrc + (kt) * 32 + p * 8, As + p * 512 + lane * 8);  \
            gload16(Bsrc + (kt) * 32 + p * 8, Bs + p * 512 + lane * 8);  \
        }                                                                \
    } while (0)

    const int fr = lane & 15;
    const int kg = lane >> 4;          // k-chunk for this lane's fragment
    const int rd = kg * 512;           // chunk-major base offset

    f32x4 acc[4][4];
#pragma unroll
    for (int m = 0; m < 4; ++m)
#pragma unroll
        for (int n = 0; n < 4; ++n) acc[m][n] = {0.f, 0.f, 0.f, 0.f};

    STAGE1(0);
    const int NKT = Dn / 32;  // 16
    for (int kt = 0; kt < NKT; ++kt) {
        asm volatile("s_waitcnt vmcnt(0)" ::: "memory");
        f16x8 af[4], bf[4];
#pragma unroll
        for (int m = 0; m < 4; ++m)
            af[m] = *reinterpret_cast<const f16x8*>(As + rd + (m * 16 + fr) * 8);
#pragma unroll
        for (int n = 0; n < 4; ++n)
            bf[n] = *reinterpret_cast<const f16x8*>(Bs + rd + (n * 16 + fr) * 8);
        asm volatile("s_waitcnt lgkmcnt(0)" ::: "memory");
        if (kt + 1 < NKT) STAGE1(kt + 1);
        __builtin_amdgcn_s_setprio(1);
#pragma unroll
        for (int m = 0; m < 4; ++m)
#pragma unroll
            for (int n = 0; n < 4; ++n)
                acc[m][n] = __builtin_amdgcn_mfma_f32_16x16x32_f16(af[m], bf[n], acc[m][n], 0, 0, 0);
        __builtin_amdgcn_s_setprio(0);
    }
#undef STAGE1

    float b1v[4];
#pragma unroll
    for (int n = 0; n < 4; ++n) b1v[n] = b1[(size_t)e * Fn + nBase + n * 16 + fr];
#pragma unroll
    for (int m = 0; m < 4; ++m) {
#pragma unroll
        for (int j = 0; j < 4; ++j) {
            int i = rowBase + m * 16 + (lane >> 4) * 4 + j;
            if (i < rowEnd) {
#pragma unroll
                for (int n = 0; n < 4; ++n) {
                    float g = fast_gelu(acc[m][n][j] + b1v[n]);
                    hbuf[(size_t)i * Fn + nBase + n * 16 + fr] = (_Float16)g;
                }
            }
        }
    }
}

// ---------------- GEMM2: out = (h @ W2 + b2) * prob ----------------
// ONE WAVE per block, tile 64x32, BK=64, 12 KB LDS (chunk-major, conflict-free).
__global__ __launch_bounds__(64) void gemm2_kernel(
    const _Float16* __restrict__ hbuf, const _Float16* __restrict__ W2T,
    const float* __restrict__ b2, const int* __restrict__ order,
    const float* __restrict__ scale,
    const int* __restrict__ nTiles, const int* __restrict__ tileExpert,
    const int* __restrict__ tileBase, const int* __restrict__ tileEnd,
    float* __restrict__ out)
{
    __shared__ _Float16 As[64 * 64];   // chunk-major: As[c*64+r], c=0..7
    __shared__ _Float16 Bs[32 * 64];   // chunk-major: Bs[c*32+r], c=0..7
    const int bt = blockIdx.x;
    if (bt >= *nTiles) return;
    const int e = tileExpert[bt], rowBase = tileBase[bt], rowEnd = tileEnd[bt];
    const int nBase = blockIdx.y * 32;
    const int lane = threadIdx.x;

    const _Float16* Asrc = hbuf + (size_t)min(rowBase + lane, Tn - 1) * Fn;
    // B: 32 rows; lane covers row lane&31, chunks c = 2p + (lane>>5)
    const _Float16* Bsrc = W2T + (size_t)e * Fn * Dn + (size_t)(nBase + (lane & 31)) * Fn
                         + (lane >> 5) * 8;

#define STAGE2(kt) do {                                                  \
        _Pragma("unroll")                                                \
        for (int p = 0; p < 8; ++p)                                      \
            gload16(Asrc + (kt) * 64 + p * 8, As + p * 512 + lane * 8);  \
        _Pragma("unroll")                                                \
        for (int p = 0; p < 4; ++p)                                      \
            gload16(Bsrc + (kt) * 64 + p * 16, Bs + p * 512 + lane * 8); \
    } while (0)

    const int fr = lane & 15;
    const int kg = lane >> 4;

    f32x4 acc[4][2];
#pragma unroll
    for (int m = 0; m < 4; ++m)
#pragma unroll
        for (int n = 0; n < 2; ++n) acc[m][n] = {0.f, 0.f, 0.f, 0.f};

    STAGE2(0);
    const int NKT = Fn / 64;  // 32
    for (int kt = 0; kt < NKT; ++kt) {
        asm volatile("s_waitcnt vmcnt(0)" ::: "memory");
        f16x8 af[4][2], bf[2][2];
#pragma unroll
        for (int ks = 0; ks < 2; ++ks) {
            const int c = ks * 4 + kg;
#pragma unroll
            for (int m = 0; m < 4; ++m)
                af[m][ks] = *reinterpret_cast<const f16x8*>(As + c * 512 + (m * 16 + fr) * 8);
#pragma unroll
            for (int n = 0; n < 2; ++n)
                bf[n][ks] = *reinterpret_cast<const f16x8*>(Bs + c * 256 + (n * 16 + fr) * 8);
        }
        asm volatile("s_waitcnt lgkmcnt(0)" ::: "memory");
        if (kt + 1 < NKT) STAGE2(kt + 1);
        __builtin_amdgcn_s_setprio(1);
#pragma unroll
        for (int ks = 0; ks < 2; ++ks)
#pragma unroll
            for (int m = 0; m < 4; ++m)
#pragma unroll
                for (int n = 0; n < 2; ++n)
                    acc[m][n] = __builtin_amdgcn_mfma_f32_16x16x32_f16(af[m][ks], bf[n][ks], acc[m][n], 0, 0, 0);
        __builtin_amdgcn_s_setprio(0);
    }
#undef STAGE2

    float b2v[2];
#pragma unroll
    for (int n = 0; n < 2; ++n) b2v[n] = b2[(size_t)e * Dn + nBase + n * 16 + fr];
#pragma unroll
    for (int m = 0; m < 4; ++m) {
#pragma unroll
        for (int j = 0; j < 4; ++j) {
            int i = rowBase + m * 16 + (lane >> 4) * 4 + j;
            if (i < rowEnd) {
                int tok = order[i];
                float s = scale[tok];
#pragma unroll
                for (int n = 0; n < 2; ++n)
                    out[(size_t)tok * Dn + nBase + n * 16 + fr] = (acc[m][n][j] + b2v[n]) * s;
            }
        }
    }
}

extern "C" void kernel_launch(void* const* d_in, const int* in_sizes, int n_in,
                              void* d_out, int out_size, void* d_ws, size_t ws_size,
                              hipStream_t stream) {
    const float* x  = (const float*)d_in[0];
    const float* Ws = (const float*)d_in[1];
    const float* bs = (const float*)d_in[2];
    const float* W1 = (const float*)d_in[3];
    const float* b1 = (const float*)d_in[4];
    const float* W2 = (const float*)d_in[5];
    const float* b2 = (const float*)d_in[6];
    float* out = (float*)d_out;

    char* ws = (char*)d_ws;
    int* nTiles      = (int*)(ws + 0);
    int* tileExpert  = (int*)(ws + 256);
    int* tileBase    = (int*)(ws + 1024);
    int* tileEnd     = (int*)(ws + 2048);
    int* route       = (int*)(ws + 4096);
    float* scale     = (float*)(ws + 4096 + 4 * Tn);
    int* poslocal    = (int*)(ws + 4096 + 8 * Tn);
    int* order       = (int*)(ws + 4096 + 12 * Tn);
    int* blockCounts = (int*)(ws + 4096 + 16 * Tn);
    int* base        = (int*)(ws + 4096 + 16 * Tn + 8192);
    _Float16* x16    = (_Float16*)(ws + (1 << 20));
    _Float16* W1T    = x16 + (size_t)Tn * Dn;
    _Float16* W2T    = W1T + (size_t)En * Dn * Fn;
    _Float16* hbuf   = W2T + (size_t)En * Fn * Dn;

    router_kernel<<<256, 256, 0, stream>>>(x, Ws, bs, x16, route, scale, poslocal, blockCounts);
    plan_kernel<<<1, 256, 0, stream>>>(blockCounts, base, nTiles, tileExpert, tileBase, tileEnd);
    scatter_kernel<<<Tn / 256, 256, 0, stream>>>(route, poslocal, base, order);
    transpose_cvt_kernel<<<4096, 256, 0, stream>>>(W1, W2, W1T, W2T);
    gemm1_kernel<<<dim3(MAXTILES, Fn / 64), 64, 0, stream>>>(
        x16, W1T, b1, order, nTiles, tileExpert, tileBase, tileEnd, hbuf);
    gemm2_kernel<<<dim3(MAXTILES, Dn / 32), 64, 0, stream>>>(
        hbuf, W2T, b2, order, scale, nTiles, tileExpert, tileBase, tileEnd, out);
}

// Round 11
// 162.047 us; speedup vs baseline: 1.9490x; 1.9490x over previous
//
#include <hip/hip_runtime.h>
#include <hip/hip_fp16.h>
#include <cmath>

#define Tn 8192
#define Dn 512
#define Fn 2048
#define En 8

typedef _Float16 f16x8 __attribute__((ext_vector_type(8)));
typedef _Float16 f16x4 __attribute__((ext_vector_type(4)));
typedef float f32x4 __attribute__((ext_vector_type(4)));

#define MAXTILES 136    // ceil(Tn/64) + En

__device__ __forceinline__ void gload16(const void* g, void* l) {
    __builtin_amdgcn_global_load_lds(
        (const __attribute__((address_space(1))) unsigned int*)g,
        (__attribute__((address_space(3))) unsigned int*)l, 16, 0, 0);
}

// A&S 7.1.26 rational erf, |eps| <= 1.5e-7
__device__ __forceinline__ float fast_gelu(float v) {
    float z = fabsf(v) * 0.70710678118654752f;
    float t = 1.0f / fmaf(0.3275911f, z, 1.0f);
    float p = t * fmaf(t, fmaf(t, fmaf(t, fmaf(t, 1.061405429f, -1.453152027f),
                                       1.421413741f), -0.284496736f), 0.254829592f);
    float e = __expf(-z * z);
    float erfa = fmaf(-p, e, 1.0f);                 // erf(|z|)
    float phi = 0.5f + copysignf(0.5f * erfa, v);   // 0.5*(1+erf(v/sqrt2))
    return v * phi;
}

// ---------------- router: logits, softmax top-1, hist + x->fp16 cvt ----------------
__global__ __launch_bounds__(256) void router_kernel(
    const float* __restrict__ x, const float* __restrict__ Ws,
    const float* __restrict__ bs, _Float16* __restrict__ x16,
    int* __restrict__ route, float* __restrict__ scale,
    int* __restrict__ poslocal, int* __restrict__ blockCounts)
{
    __shared__ int hist[8];
    const int tid = threadIdx.x;
    if (tid < 8) hist[tid] = 0;
    __syncthreads();

    const int lane = tid & 63;
    const int w = tid >> 6;
    const int tokBase = blockIdx.x * 32 + w * 8;

    float wreg[8][8];
#pragma unroll
    for (int j = 0; j < 4; ++j) {
        const float4* p = reinterpret_cast<const float4*>(Ws + (4 * lane + j) * En);
        float4 a = p[0], b = p[1];
        wreg[j][0] = a.x; wreg[j][1] = a.y; wreg[j][2] = a.z; wreg[j][3] = a.w;
        wreg[j][4] = b.x; wreg[j][5] = b.y; wreg[j][6] = b.z; wreg[j][7] = b.w;
    }
#pragma unroll
    for (int j = 0; j < 4; ++j) {
        const float4* p = reinterpret_cast<const float4*>(Ws + (256 + 4 * lane + j) * En);
        float4 a = p[0], b = p[1];
        wreg[4 + j][0] = a.x; wreg[4 + j][1] = a.y; wreg[4 + j][2] = a.z; wreg[4 + j][3] = a.w;
        wreg[4 + j][4] = b.x; wreg[4 + j][5] = b.y; wreg[4 + j][6] = b.z; wreg[4 + j][7] = b.w;
    }
    float bsv[8];
#pragma unroll
    for (int e = 0; e < 8; ++e) bsv[e] = bs[e];

    for (int it = 0; it < 8; ++it) {
        int t = tokBase + it;
        const float4* xr = reinterpret_cast<const float4*>(x + (size_t)t * Dn);
        float4 v0 = xr[lane];
        float4 v1 = xr[64 + lane];
        f16x4 h0, h1;
        h0[0] = (_Float16)v0.x; h0[1] = (_Float16)v0.y; h0[2] = (_Float16)v0.z; h0[3] = (_Float16)v0.w;
        h1[0] = (_Float16)v1.x; h1[1] = (_Float16)v1.y; h1[2] = (_Float16)v1.z; h1[3] = (_Float16)v1.w;
        *reinterpret_cast<f16x4*>(x16 + (size_t)t * Dn + 4 * lane) = h0;
        *reinterpret_cast<f16x4*>(x16 + (size_t)t * Dn + 256 + 4 * lane) = h1;

        float xv[8] = {v0.x, v0.y, v0.z, v0.w, v1.x, v1.y, v1.z, v1.w};
        float part[8];
#pragma unroll
        for (int e = 0; e < 8; ++e) part[e] = 0.f;
#pragma unroll
        for (int j = 0; j < 8; ++j)
#pragma unroll
            for (int e = 0; e < 8; ++e) part[e] = fmaf(xv[j], wreg[j][e], part[e]);
#pragma unroll
        for (int s = 32; s > 0; s >>= 1) {
#pragma unroll
            for (int e = 0; e < 8; ++e) part[e] += __shfl_xor(part[e], s);
        }
        if (lane == 0) {
            float lg[8];
            lg[0] = part[0] + bsv[0];
            float m = lg[0]; int am = 0;
#pragma unroll
            for (int e = 1; e < 8; ++e) {
                lg[e] = part[e] + bsv[e];
                if (lg[e] > m) { m = lg[e]; am = e; }   // first-max tie rule
            }
            float sum = 0.f;
#pragma unroll
            for (int e = 0; e < 8; ++e) sum += expf(lg[e] - m);
            route[t] = am;
            scale[t] = 1.0f / sum;                 // top-1 softmax prob
            poslocal[t] = atomicAdd(&hist[am], 1); // LDS atomic: local rank
        }
    }
    __syncthreads();
    if (tid < 8) blockCounts[blockIdx.x * 8 + tid] = hist[tid];
}

// ---------------- plan: prefix sums (no atomics) + tile table ----------------
__global__ __launch_bounds__(256) void plan_kernel(
    const int* __restrict__ blockCounts,   // [256][8]
    int* __restrict__ base,                // [256][8] out
    int* __restrict__ nTiles, int* __restrict__ tileExpert,
    int* __restrict__ tileBase, int* __restrict__ tileEnd)
{
    __shared__ int cnt[256 * 8];
    __shared__ int groupSum[32 * 8];
    __shared__ int groupBase[32 * 8];
    __shared__ int totals[8];
    __shared__ int offsets_s[8];
    const int tid = threadIdx.x;
    for (int i = tid; i < 2048; i += 256) cnt[i] = blockCounts[i];
    __syncthreads();
    const int e = tid & 7, g = tid >> 3;
    {
        int s = 0;
#pragma unroll
        for (int b = g * 8; b < g * 8 + 8; ++b) s += cnt[b * 8 + e];
        groupSum[g * 8 + e] = s;
    }
    __syncthreads();
    if (tid < 8) {
        int run = 0;
        for (int gg = 0; gg < 32; ++gg) {
            groupBase[gg * 8 + tid] = run;
            run += groupSum[gg * 8 + tid];
        }
        totals[tid] = run;
    }
    __syncthreads();
    if (tid == 0) {
        int off = 0, nt = 0;
        for (int ee = 0; ee < En; ++ee) {
            offsets_s[ee] = off;
            int c = totals[ee];
            int tiles = (c + 63) / 64;
            for (int r = 0; r < tiles; ++r) {
                tileExpert[nt] = ee;
                tileBase[nt] = off + r * 64;
                tileEnd[nt] = off + c;
                ++nt;
            }
            off += c;
        }
        *nTiles = nt;
    }
    __syncthreads();
    {
        int run = offsets_s[e] + groupBase[g * 8 + e];
#pragma unroll
        for (int b = g * 8; b < g * 8 + 8; ++b) {
            base[b * 8 + e] = run;
            run += cnt[b * 8 + e];
        }
    }
}

// ---------------- scatter: pure writes, no atomics ----------------
__global__ __launch_bounds__(256) void scatter_kernel(
    const int* __restrict__ route, const int* __restrict__ poslocal,
    const int* __restrict__ base, int* __restrict__ order)
{
    int t = blockIdx.x * 256 + threadIdx.x;
    if (t >= Tn) return;
    int e = route[t];
    int rb = t >> 5;
    order[base[rb * 8 + e] + poslocal[t]] = t;
}

// ---------------- transpose + fp32->fp16 for W1, W2 ----------------
__global__ __launch_bounds__(256) void transpose_cvt_kernel(
    const float* __restrict__ W1, const float* __restrict__ W2,
    _Float16* __restrict__ W1T, _Float16* __restrict__ W2T)
{
    __shared__ float tile[64][65];
    int bx = blockIdx.x;
    const float* in; _Float16* outp; int R, C, tR, tC;
    if (bx < 2048) {            // W1[e]: [D][F] -> W1T[e]: [F][D]
        int e = bx >> 8, t = bx & 255;
        R = Dn; C = Fn; tR = t >> 5; tC = t & 31;
        in = W1 + (size_t)e * Dn * Fn;
        outp = W1T + (size_t)e * Dn * Fn;
    } else {                    // W2[e]: [F][D] -> W2T[e]: [D][F]
        int b2 = bx - 2048;
        int e = b2 >> 8, t = b2 & 255;
        R = Fn; C = Dn; tR = t >> 3; tC = t & 7;
        in = W2 + (size_t)e * Fn * Dn;
        outp = W2T + (size_t)e * Fn * Dn;
    }
    int r0 = tR * 64, c0 = tC * 64;
    int row = threadIdx.x >> 2, cq = threadIdx.x & 3;
#pragma unroll
    for (int i = 0; i < 4; ++i) {
        float4 v = *reinterpret_cast<const float4*>(in + (size_t)(r0 + row) * C + c0 + cq * 16 + i * 4);
        tile[row][cq * 16 + i * 4 + 0] = v.x;
        tile[row][cq * 16 + i * 4 + 1] = v.y;
        tile[row][cq * 16 + i * 4 + 2] = v.z;
        tile[row][cq * 16 + i * 4 + 3] = v.w;
    }
    __syncthreads();
    int col = threadIdx.x >> 2, rq = threadIdx.x & 3;
    f16x8 o0, o1;
#pragma unroll
    for (int i = 0; i < 8; ++i) o0[i] = (_Float16)tile[rq * 16 + i][col];
#pragma unroll
    for (int i = 0; i < 8; ++i) o1[i] = (_Float16)tile[rq * 16 + 8 + i][col];
    size_t base = (size_t)(c0 + col) * R + r0 + rq * 16;
    *reinterpret_cast<f16x8*>(outp + base) = o0;
    *reinterpret_cast<f16x8*>(outp + base + 8) = o1;
}

// ---------------- GEMM1: h = gelu(Xg @ W1 + b1) ----------------
// R7 structure (proven): ONE WAVE per block, tile 64x64, BK=64, single LDS buffer,
// gload_lds + XOR-8 swizzle, loop: STAGE -> vmcnt(0) -> frags -> lgkmcnt(0) -> STAGE(next) -> MFMA.
// Delta vs R7: fast_gelu epilogue (erff -> rational erf).
__global__ __launch_bounds__(64) void gemm1_kernel(
    const _Float16* __restrict__ x16, const _Float16* __restrict__ W1T,
    const float* __restrict__ b1, const int* __restrict__ order,
    const int* __restrict__ nTiles, const int* __restrict__ tileExpert,
    const int* __restrict__ tileBase, const int* __restrict__ tileEnd,
    _Float16* __restrict__ hbuf)
{
    __shared__ _Float16 As[64 * 64];   // 8 KB
    __shared__ _Float16 Bs[64 * 64];   // 8 KB
    const int bt = blockIdx.x;
    if (bt >= *nTiles) return;
    const int e = tileExpert[bt], rowBase = tileBase[bt], rowEnd = tileEnd[bt];
    const int nBase = blockIdx.y * 64;
    const int lane = threadIdx.x;

    const int swc = ((lane & 7) ^ (lane >> 3)) * 8;
    const _Float16* Asrc[8];
    const _Float16* Bsrc[8];
#pragma unroll
    for (int p = 0; p < 8; ++p) {
        int r = p * 8 + (lane >> 3);
        int tok = order[min(rowBase + r, Tn - 1)];
        Asrc[p] = x16 + (size_t)tok * Dn + swc;
        Bsrc[p] = W1T + (size_t)e * Dn * Fn + (size_t)(nBase + r) * Dn + swc;
    }

#define STAGE1(kt) do {                                                  \
        _Pragma("unroll")                                                \
        for (int p = 0; p < 8; ++p) {                                    \
            gload16(Asrc[p] + (kt) * 64, As + (p * 64 + lane) * 8);      \
            gload16(Bsrc[p] + (kt) * 64, Bs + (p * 64 + lane) * 8);      \
        }                                                                \
    } while (0)

    const int fr = lane & 15;
    const int off0 = (((lane >> 4))     ^ (lane & 7)) * 8;
    const int off1 = ((4 + (lane >> 4)) ^ (lane & 7)) * 8;

    f32x4 acc[4][4];
#pragma unroll
    for (int m = 0; m < 4; ++m)
#pragma unroll
        for (int n = 0; n < 4; ++n) acc[m][n] = {0.f, 0.f, 0.f, 0.f};

    STAGE1(0);
    const int NKT = Dn / 64;  // 8
    for (int kt = 0; kt < NKT; ++kt) {
        asm volatile("s_waitcnt vmcnt(0)" ::: "memory");
        f16x8 af[4][2], bf[4][2];
#pragma unroll
        for (int m = 0; m < 4; ++m) {
            af[m][0] = *reinterpret_cast<const f16x8*>(As + (m * 16 + fr) * 64 + off0);
            af[m][1] = *reinterpret_cast<const f16x8*>(As + (m * 16 + fr) * 64 + off1);
        }
#pragma unroll
        for (int n = 0; n < 4; ++n) {
            bf[n][0] = *reinterpret_cast<const f16x8*>(Bs + (n * 16 + fr) * 64 + off0);
            bf[n][1] = *reinterpret_cast<const f16x8*>(Bs + (n * 16 + fr) * 64 + off1);
        }
        asm volatile("s_waitcnt lgkmcnt(0)" ::: "memory");
        if (kt + 1 < NKT) STAGE1(kt + 1);
        __builtin_amdgcn_s_setprio(1);
#pragma unroll
        for (int ks = 0; ks < 2; ++ks)
#pragma unroll
            for (int m = 0; m < 4; ++m)
#pragma unroll
                for (int n = 0; n < 4; ++n)
                    acc[m][n] = __builtin_amdgcn_mfma_f32_16x16x32_f16(af[m][ks], bf[n][ks], acc[m][n], 0, 0, 0);
        __builtin_amdgcn_s_setprio(0);
    }
#undef STAGE1

    float b1v[4];
#pragma unroll
    for (int n = 0; n < 4; ++n) b1v[n] = b1[(size_t)e * Fn + nBase + n * 16 + fr];
#pragma unroll
    for (int m = 0; m < 4; ++m) {
#pragma unroll
        for (int j = 0; j < 4; ++j) {
            int i = rowBase + m * 16 + (lane >> 4) * 4 + j;
            if (i < rowEnd) {
#pragma unroll
                for (int n = 0; n < 4; ++n) {
                    float g = fast_gelu(acc[m][n][j] + b1v[n]);
                    hbuf[(size_t)i * Fn + nBase + n * 16 + fr] = (_Float16)g;
                }
            }
        }
    }
}

// ---------------- GEMM2: out = (h @ W2 + b2) * prob ----------------
// ONE WAVE per block, tile 64x32, BK=32, REG-STAGED (global->VGPR->LDS):
// all waits are compiler-inserted COUNTED vmcnt/lgkmcnt (no gload_lds aliasing).
// LDS rows padded to 40 elems -> conflict-light without swizzle. 7.5 KB LDS.
__global__ __launch_bounds__(64) void gemm2_kernel(
    const _Float16* __restrict__ hbuf, const _Float16* __restrict__ W2T,
    const float* __restrict__ b2, const int* __restrict__ order,
    const float* __restrict__ scale,
    const int* __restrict__ nTiles, const int* __restrict__ tileExpert,
    const int* __restrict__ tileBase, const int* __restrict__ tileEnd,
    float* __restrict__ out)
{
    __shared__ _Float16 As[64 * 40];   // 5 KB, row r at r*40
    __shared__ _Float16 Bs[32 * 40];   // 2.5 KB
    const int bt = blockIdx.x;
    if (bt >= *nTiles) return;
    const int e = tileExpert[bt], rowBase = tileBase[bt], rowEnd = tileEnd[bt];
    const int nBase = blockIdx.y * 32;
    const int lane = threadIdx.x;

    // staging map: pass p covers rows p*16 + (lane>>2), k-chunk (lane&3)*8
    const int srow = lane >> 2;
    const int sc = (lane & 3) * 8;
    const _Float16* Ap[4];
#pragma unroll
    for (int p = 0; p < 4; ++p)
        Ap[p] = hbuf + (size_t)min(rowBase + p * 16 + srow, Tn - 1) * Fn + sc;
    const _Float16* Bp[2];
#pragma unroll
    for (int p = 0; p < 2; ++p)
        Bp[p] = W2T + (size_t)e * Fn * Dn + (size_t)(nBase + p * 16 + srow) * Fn + sc;
    _Float16* AsW = As + srow * 40 + sc;   // + p*16*40
    _Float16* BsW = Bs + srow * 40 + sc;

#define LOAD2(ra, rb, kt) do {                                           \
        _Pragma("unroll")                                                \
        for (int p = 0; p < 4; ++p)                                      \
            ra[p] = *reinterpret_cast<const f16x8*>(Ap[p] + (kt) * 32);  \
        _Pragma("unroll")                                                \
        for (int p = 0; p < 2; ++p)                                      \
            rb[p] = *reinterpret_cast<const f16x8*>(Bp[p] + (kt) * 32);  \
    } while (0)

#define STORE2(ra, rb) do {                                              \
        _Pragma("unroll")                                                \
        for (int p = 0; p < 4; ++p)                                      \
            *reinterpret_cast<f16x8*>(AsW + p * 640) = ra[p];            \
        _Pragma("unroll")                                                \
        for (int p = 0; p < 2; ++p)                                      \
            *reinterpret_cast<f16x8*>(BsW + p * 640) = rb[p];            \
    } while (0)

    const int fr = lane & 15;
    const int kg = (lane >> 4) * 8;    // k-offset within 32-wide row

#define COMPUTE2() do {                                                  \
        f16x8 af[4], bf[2];                                              \
        _Pragma("unroll")                                                \
        for (int m = 0; m < 4; ++m)                                      \
            af[m] = *reinterpret_cast<const f16x8*>(As + (m * 16 + fr) * 40 + kg); \
        _Pragma("unroll")                                                \
        for (int n = 0; n < 2; ++n)                                      \
            bf[n] = *reinterpret_cast<const f16x8*>(Bs + (n * 16 + fr) * 40 + kg); \
        __builtin_amdgcn_s_setprio(1);                                   \
        _Pragma("unroll")                                                \
        for (int m = 0; m < 4; ++m)                                      \
            _Pragma("unroll")                                            \
            for (int n = 0; n < 2; ++n)                                  \
                acc[m][n] = __builtin_amdgcn_mfma_f32_16x16x32_f16(af[m], bf[n], acc[m][n], 0, 0, 0); \
        __builtin_amdgcn_s_setprio(0);                                   \
    } while (0)

    f32x4 acc[4][2];
#pragma unroll
    for (int m = 0; m < 4; ++m)
#pragma unroll
        for (int n = 0; n < 2; ++n) acc[m][n] = {0.f, 0.f, 0.f, 0.f};

    f16x8 ra0[4], rb0[2], ra1[4], rb1[2];
    LOAD2(ra0, rb0, 0);
    const int NKT = Fn / 32;  // 64 (even)
    for (int kt = 0; kt < NKT; kt += 2) {
        LOAD2(ra1, rb1, kt + 1);
        STORE2(ra0, rb0);
        COMPUTE2();
        if (kt + 2 < NKT) LOAD2(ra0, rb0, kt + 2);
        STORE2(ra1, rb1);
        COMPUTE2();
    }
#undef LOAD2
#undef STORE2
#undef COMPUTE2

    float b2v[2];
#pragma unroll
    for (int n = 0; n < 2; ++n) b2v[n] = b2[(size_t)e * Dn + nBase + n * 16 + fr];
#pragma unroll
    for (int m = 0; m < 4; ++m) {
#pragma unroll
        for (int j = 0; j < 4; ++j) {
            int i = rowBase + m * 16 + (lane >> 4) * 4 + j;
            if (i < rowEnd) {
                int tok = order[i];
                float s = scale[tok];
#pragma unroll
                for (int n = 0; n < 2; ++n)
                    out[(size_t)tok * Dn + nBase + n * 16 + fr] = (acc[m][n][j] + b2v[n]) * s;
            }
        }
    }
}

extern "C" void kernel_launch(void* const* d_in, const int* in_sizes, int n_in,
                              void* d_out, int out_size, void* d_ws, size_t ws_size,
                              hipStream_t stream) {
    const float* x  = (const float*)d_in[0];
    const float* Ws = (const float*)d_in[1];
    const float* bs = (const float*)d_in[2];
    const float* W1 = (const float*)d_in[3];
    const float* b1 = (const float*)d_in[4];
    const float* W2 = (const float*)d_in[5];
    const float* b2 = (const float*)d_in[6];
    float* out = (float*)d_out;

    char* ws = (char*)d_ws;
    int* nTiles      = (int*)(ws + 0);
    int* tileExpert  = (int*)(ws + 256);
    int* tileBase    = (int*)(ws + 1024);
    int* tileEnd     = (int*)(ws + 2048);
    int* route       = (int*)(ws + 4096);
    float* scale     = (float*)(ws + 4096 + 4 * Tn);
    int* poslocal    = (int*)(ws + 4096 + 8 * Tn);
    int* order       = (int*)(ws + 4096 + 12 * Tn);
    int* blockCounts = (int*)(ws + 4096 + 16 * Tn);
    int* base        = (int*)(ws + 4096 + 16 * Tn + 8192);
    _Float16* x16    = (_Float16*)(ws + (1 << 20));
    _Float16* W1T    = x16 + (size_t)Tn * Dn;
    _Float16* W2T    = W1T + (size_t)En * Dn * Fn;
    _Float16* hbuf   = W2T + (size_t)En * Fn * Dn;

    router_kernel<<<256, 256, 0, stream>>>(x, Ws, bs, x16, route, scale, poslocal, blockCounts);
    plan_kernel<<<1, 256, 0, stream>>>(blockCounts, base, nTiles, tileExpert, tileBase, tileEnd);
    scatter_kernel<<<Tn / 256, 256, 0, stream>>>(route, poslocal, base, order);
    transpose_cvt_kernel<<<4096, 256, 0, stream>>>(W1, W2, W1T, W2T);
    gemm1_kernel<<<dim3(MAXTILES, Fn / 64), 64, 0, stream>>>(
        x16, W1T, b1, order, nTiles, tileExpert, tileBase, tileEnd, hbuf);
    gemm2_kernel<<<dim3(MAXTILES, Dn / 32), 64, 0, stream>>>(
        hbuf, W2T, b2, order, scale, nTiles, tileExpert, tileBase, tileEnd, out);
}

// Round 12
// 129.031 us; speedup vs baseline: 2.4478x; 1.2559x over previous
//
#include <hip/hip_runtime.h>
#include <hip/hip_fp16.h>
#include <cmath>

#define Tn 8192
#define Dn 512
#define Fn 2048
#define En 8

typedef _Float16 f16x8 __attribute__((ext_vector_type(8)));
typedef _Float16 f16x4 __attribute__((ext_vector_type(4)));
typedef float f32x4 __attribute__((ext_vector_type(4)));

#define MAXTILES 136    // ceil(Tn/64) + En = 8*17, divisible by 8 XCDs

__device__ __forceinline__ void gload16(const void* g, void* l) {
    __builtin_amdgcn_global_load_lds(
        (const __attribute__((address_space(1))) unsigned int*)g,
        (__attribute__((address_space(3))) unsigned int*)l, 16, 0, 0);
}

// A&S 7.1.26 rational erf, |eps| <= 1.5e-7
__device__ __forceinline__ float fast_gelu(float v) {
    float z = fabsf(v) * 0.70710678118654752f;
    float t = 1.0f / fmaf(0.3275911f, z, 1.0f);
    float p = t * fmaf(t, fmaf(t, fmaf(t, fmaf(t, 1.061405429f, -1.453152027f),
                                       1.421413741f), -0.284496736f), 0.254829592f);
    float e = __expf(-z * z);
    float erfa = fmaf(-p, e, 1.0f);                 // erf(|z|)
    float phi = 0.5f + copysignf(0.5f * erfa, v);   // 0.5*(1+erf(v/sqrt2))
    return v * phi;
}

// ---------------- router: logits, softmax top-1, hist + x->fp16 cvt ----------------
__global__ __launch_bounds__(256) void router_kernel(
    const float* __restrict__ x, const float* __restrict__ Ws,
    const float* __restrict__ bs, _Float16* __restrict__ x16,
    int* __restrict__ route, float* __restrict__ scale,
    int* __restrict__ poslocal, int* __restrict__ blockCounts)
{
    __shared__ int hist[8];
    const int tid = threadIdx.x;
    if (tid < 8) hist[tid] = 0;
    __syncthreads();

    const int lane = tid & 63;
    const int w = tid >> 6;
    const int tokBase = blockIdx.x * 32 + w * 8;

    float wreg[8][8];
#pragma unroll
    for (int j = 0; j < 4; ++j) {
        const float4* p = reinterpret_cast<const float4*>(Ws + (4 * lane + j) * En);
        float4 a = p[0], b = p[1];
        wreg[j][0] = a.x; wreg[j][1] = a.y; wreg[j][2] = a.z; wreg[j][3] = a.w;
        wreg[j][4] = b.x; wreg[j][5] = b.y; wreg[j][6] = b.z; wreg[j][7] = b.w;
    }
#pragma unroll
    for (int j = 0; j < 4; ++j) {
        const float4* p = reinterpret_cast<const float4*>(Ws + (256 + 4 * lane + j) * En);
        float4 a = p[0], b = p[1];
        wreg[4 + j][0] = a.x; wreg[4 + j][1] = a.y; wreg[4 + j][2] = a.z; wreg[4 + j][3] = a.w;
        wreg[4 + j][4] = b.x; wreg[4 + j][5] = b.y; wreg[4 + j][6] = b.z; wreg[4 + j][7] = b.w;
    }
    float bsv[8];
#pragma unroll
    for (int e = 0; e < 8; ++e) bsv[e] = bs[e];

    for (int it = 0; it < 8; ++it) {
        int t = tokBase + it;
        const float4* xr = reinterpret_cast<const float4*>(x + (size_t)t * Dn);
        float4 v0 = xr[lane];
        float4 v1 = xr[64 + lane];
        f16x4 h0, h1;
        h0[0] = (_Float16)v0.x; h0[1] = (_Float16)v0.y; h0[2] = (_Float16)v0.z; h0[3] = (_Float16)v0.w;
        h1[0] = (_Float16)v1.x; h1[1] = (_Float16)v1.y; h1[2] = (_Float16)v1.z; h1[3] = (_Float16)v1.w;
        *reinterpret_cast<f16x4*>(x16 + (size_t)t * Dn + 4 * lane) = h0;
        *reinterpret_cast<f16x4*>(x16 + (size_t)t * Dn + 256 + 4 * lane) = h1;

        float xv[8] = {v0.x, v0.y, v0.z, v0.w, v1.x, v1.y, v1.z, v1.w};
        float part[8];
#pragma unroll
        for (int e = 0; e < 8; ++e) part[e] = 0.f;
#pragma unroll
        for (int j = 0; j < 8; ++j)
#pragma unroll
            for (int e = 0; e < 8; ++e) part[e] = fmaf(xv[j], wreg[j][e], part[e]);
#pragma unroll
        for (int s = 32; s > 0; s >>= 1) {
#pragma unroll
            for (int e = 0; e < 8; ++e) part[e] += __shfl_xor(part[e], s);
        }
        if (lane == 0) {
            float lg[8];
            lg[0] = part[0] + bsv[0];
            float m = lg[0]; int am = 0;
#pragma unroll
            for (int e = 1; e < 8; ++e) {
                lg[e] = part[e] + bsv[e];
                if (lg[e] > m) { m = lg[e]; am = e; }   // first-max tie rule
            }
            float sum = 0.f;
#pragma unroll
            for (int e = 0; e < 8; ++e) sum += expf(lg[e] - m);
            route[t] = am;
            scale[t] = 1.0f / sum;                 // top-1 softmax prob
            poslocal[t] = atomicAdd(&hist[am], 1); // LDS atomic: local rank
        }
    }
    __syncthreads();
    if (tid < 8) blockCounts[blockIdx.x * 8 + tid] = hist[tid];
}

// ---------------- plan: prefix sums (no atomics) + tile table ----------------
__global__ __launch_bounds__(256) void plan_kernel(
    const int* __restrict__ blockCounts,   // [256][8]
    int* __restrict__ base,                // [256][8] out
    int* __restrict__ nTiles, int* __restrict__ tileExpert,
    int* __restrict__ tileBase, int* __restrict__ tileEnd)
{
    __shared__ int cnt[256 * 8];
    __shared__ int groupSum[32 * 8];
    __shared__ int groupBase[32 * 8];
    __shared__ int totals[8];
    __shared__ int offsets_s[8];
    const int tid = threadIdx.x;
    for (int i = tid; i < 2048; i += 256) cnt[i] = blockCounts[i];
    __syncthreads();
    const int e = tid & 7, g = tid >> 3;
    {
        int s = 0;
#pragma unroll
        for (int b = g * 8; b < g * 8 + 8; ++b) s += cnt[b * 8 + e];
        groupSum[g * 8 + e] = s;
    }
    __syncthreads();
    if (tid < 8) {
        int run = 0;
        for (int gg = 0; gg < 32; ++gg) {
            groupBase[gg * 8 + tid] = run;
            run += groupSum[gg * 8 + tid];
        }
        totals[tid] = run;
    }
    __syncthreads();
    if (tid == 0) {
        int off = 0, nt = 0;
        for (int ee = 0; ee < En; ++ee) {
            offsets_s[ee] = off;
            int c = totals[ee];
            int tiles = (c + 63) / 64;
            for (int r = 0; r < tiles; ++r) {
                tileExpert[nt] = ee;
                tileBase[nt] = off + r * 64;
                tileEnd[nt] = off + c;
                ++nt;
            }
            off += c;
        }
        *nTiles = nt;
    }
    __syncthreads();
    {
        int run = offsets_s[e] + groupBase[g * 8 + e];
#pragma unroll
        for (int b = g * 8; b < g * 8 + 8; ++b) {
            base[b * 8 + e] = run;
            run += cnt[b * 8 + e];
        }
    }
}

// ---------------- scatter: pure writes, no atomics ----------------
__global__ __launch_bounds__(256) void scatter_kernel(
    const int* __restrict__ route, const int* __restrict__ poslocal,
    const int* __restrict__ base, int* __restrict__ order)
{
    int t = blockIdx.x * 256 + threadIdx.x;
    if (t >= Tn) return;
    int e = route[t];
    int rb = t >> 5;
    order[base[rb * 8 + e] + poslocal[t]] = t;
}

// ---------------- transpose + fp32->fp16 for W1, W2 ----------------
__global__ __launch_bounds__(256) void transpose_cvt_kernel(
    const float* __restrict__ W1, const float* __restrict__ W2,
    _Float16* __restrict__ W1T, _Float16* __restrict__ W2T)
{
    __shared__ float tile[64][65];
    int bx = blockIdx.x;
    const float* in; _Float16* outp; int R, C, tR, tC;
    if (bx < 2048) {            // W1[e]: [D][F] -> W1T[e]: [F][D]
        int e = bx >> 8, t = bx & 255;
        R = Dn; C = Fn; tR = t >> 5; tC = t & 31;
        in = W1 + (size_t)e * Dn * Fn;
        outp = W1T + (size_t)e * Dn * Fn;
    } else {                    // W2[e]: [F][D] -> W2T[e]: [D][F]
        int b2 = bx - 2048;
        int e = b2 >> 8, t = b2 & 255;
        R = Fn; C = Dn; tR = t >> 3; tC = t & 7;
        in = W2 + (size_t)e * Fn * Dn;
        outp = W2T + (size_t)e * Fn * Dn;
    }
    int r0 = tR * 64, c0 = tC * 64;
    int row = threadIdx.x >> 2, cq = threadIdx.x & 3;
#pragma unroll
    for (int i = 0; i < 4; ++i) {
        float4 v = *reinterpret_cast<const float4*>(in + (size_t)(r0 + row) * C + c0 + cq * 16 + i * 4);
        tile[row][cq * 16 + i * 4 + 0] = v.x;
        tile[row][cq * 16 + i * 4 + 1] = v.y;
        tile[row][cq * 16 + i * 4 + 2] = v.z;
        tile[row][cq * 16 + i * 4 + 3] = v.w;
    }
    __syncthreads();
    int col = threadIdx.x >> 2, rq = threadIdx.x & 3;
    f16x8 o0, o1;
#pragma unroll
    for (int i = 0; i < 8; ++i) o0[i] = (_Float16)tile[rq * 16 + i][col];
#pragma unroll
    for (int i = 0; i < 8; ++i) o1[i] = (_Float16)tile[rq * 16 + 8 + i][col];
    size_t base = (size_t)(c0 + col) * R + r0 + rq * 16;
    *reinterpret_cast<f16x8*>(outp + base) = o0;
    *reinterpret_cast<f16x8*>(outp + base + 8) = o1;
}

// ---------------- GEMM1: h = gelu(Xg @ W1 + b1) ----------------
// R7 structure + XCD swizzle + fast_gelu. ONE WAVE per block, 64x64 tile, BK=64,
// single LDS buffer, gload_lds + XOR-8 swizzle (0 conflicts).
__global__ __launch_bounds__(64) void gemm1_kernel(
    const _Float16* __restrict__ x16, const _Float16* __restrict__ W1T,
    const float* __restrict__ b1, const int* __restrict__ order,
    const int* __restrict__ nTiles, const int* __restrict__ tileExpert,
    const int* __restrict__ tileBase, const int* __restrict__ tileEnd,
    _Float16* __restrict__ hbuf)
{
    __shared__ _Float16 As[64 * 64];   // 8 KB
    __shared__ _Float16 Bs[64 * 64];   // 8 KB
    // XCD-aware swizzle: 136 = 8*17; consecutive dispatch x%8 -> same XCD chunk
    const int bx = blockIdx.x;
    const int bt = (bx & 7) * 17 + (bx >> 3);
    if (bt >= *nTiles) return;
    const int e = tileExpert[bt], rowBase = tileBase[bt], rowEnd = tileEnd[bt];
    const int nBase = blockIdx.y * 64;
    const int lane = threadIdx.x;

    const int swc = ((lane & 7) ^ (lane >> 3)) * 8;
    const _Float16* Asrc[8];
    const _Float16* Bsrc[8];
#pragma unroll
    for (int p = 0; p < 8; ++p) {
        int r = p * 8 + (lane >> 3);
        int tok = order[min(rowBase + r, Tn - 1)];
        Asrc[p] = x16 + (size_t)tok * Dn + swc;
        Bsrc[p] = W1T + (size_t)e * Dn * Fn + (size_t)(nBase + r) * Dn + swc;
    }

#define STAGE1(kt) do {                                                  \
        _Pragma("unroll")                                                \
        for (int p = 0; p < 8; ++p) {                                    \
            gload16(Asrc[p] + (kt) * 64, As + (p * 64 + lane) * 8);      \
            gload16(Bsrc[p] + (kt) * 64, Bs + (p * 64 + lane) * 8);      \
        }                                                                \
    } while (0)

    const int fr = lane & 15;
    const int off0 = (((lane >> 4))     ^ (lane & 7)) * 8;
    const int off1 = ((4 + (lane >> 4)) ^ (lane & 7)) * 8;

    f32x4 acc[4][4];
#pragma unroll
    for (int m = 0; m < 4; ++m)
#pragma unroll
        for (int n = 0; n < 4; ++n) acc[m][n] = {0.f, 0.f, 0.f, 0.f};

    STAGE1(0);
    const int NKT = Dn / 64;  // 8
    for (int kt = 0; kt < NKT; ++kt) {
        asm volatile("s_waitcnt vmcnt(0)" ::: "memory");
        f16x8 af[4][2], bf[4][2];
#pragma unroll
        for (int m = 0; m < 4; ++m) {
            af[m][0] = *reinterpret_cast<const f16x8*>(As + (m * 16 + fr) * 64 + off0);
            af[m][1] = *reinterpret_cast<const f16x8*>(As + (m * 16 + fr) * 64 + off1);
        }
#pragma unroll
        for (int n = 0; n < 4; ++n) {
            bf[n][0] = *reinterpret_cast<const f16x8*>(Bs + (n * 16 + fr) * 64 + off0);
            bf[n][1] = *reinterpret_cast<const f16x8*>(Bs + (n * 16 + fr) * 64 + off1);
        }
        asm volatile("s_waitcnt lgkmcnt(0)" ::: "memory");
        if (kt + 1 < NKT) STAGE1(kt + 1);
        __builtin_amdgcn_s_setprio(1);
#pragma unroll
        for (int ks = 0; ks < 2; ++ks)
#pragma unroll
            for (int m = 0; m < 4; ++m)
#pragma unroll
                for (int n = 0; n < 4; ++n)
                    acc[m][n] = __builtin_amdgcn_mfma_f32_16x16x32_f16(af[m][ks], bf[n][ks], acc[m][n], 0, 0, 0);
        __builtin_amdgcn_s_setprio(0);
    }
#undef STAGE1

    float b1v[4];
#pragma unroll
    for (int n = 0; n < 4; ++n) b1v[n] = b1[(size_t)e * Fn + nBase + n * 16 + fr];
#pragma unroll
    for (int m = 0; m < 4; ++m) {
#pragma unroll
        for (int j = 0; j < 4; ++j) {
            int i = rowBase + m * 16 + (lane >> 4) * 4 + j;
            if (i < rowEnd) {
#pragma unroll
                for (int n = 0; n < 4; ++n) {
                    float g = fast_gelu(acc[m][n][j] + b1v[n]);
                    hbuf[(size_t)i * Fn + nBase + n * 16 + fr] = (_Float16)g;
                }
            }
        }
    }
}

// ---------------- GEMM2: out = (h @ W2 + b2) * prob ----------------
// R7 structure + XCD swizzle. ONE WAVE per block, 64x32 tile, K=2048, BK=64.
__global__ __launch_bounds__(64) void gemm2_kernel(
    const _Float16* __restrict__ hbuf, const _Float16* __restrict__ W2T,
    const float* __restrict__ b2, const int* __restrict__ order,
    const float* __restrict__ scale,
    const int* __restrict__ nTiles, const int* __restrict__ tileExpert,
    const int* __restrict__ tileBase, const int* __restrict__ tileEnd,
    float* __restrict__ out)
{
    __shared__ _Float16 As[64 * 64];   // 8 KB
    __shared__ _Float16 Bs[32 * 64];   // 4 KB
    const int bx = blockIdx.x;
    const int bt = (bx & 7) * 17 + (bx >> 3);
    if (bt >= *nTiles) return;
    const int e = tileExpert[bt], rowBase = tileBase[bt], rowEnd = tileEnd[bt];
    const int nBase = blockIdx.y * 32;
    const int lane = threadIdx.x;

    const int swc = ((lane & 7) ^ (lane >> 3)) * 8;
    const _Float16* Asrc[8];
    const _Float16* Bsrc[4];
#pragma unroll
    for (int p = 0; p < 8; ++p) {
        int r = p * 8 + (lane >> 3);
        Asrc[p] = hbuf + (size_t)min(rowBase + r, Tn - 1) * Fn + swc;
    }
#pragma unroll
    for (int p = 0; p < 4; ++p) {
        int r = p * 8 + (lane >> 3);
        Bsrc[p] = W2T + (size_t)e * Fn * Dn + (size_t)(nBase + r) * Fn + swc;
    }

#define STAGE2(kt) do {                                                  \
        _Pragma("unroll")                                                \
        for (int p = 0; p < 8; ++p)                                      \
            gload16(Asrc[p] + (kt) * 64, As + (p * 64 + lane) * 8);      \
        _Pragma("unroll")                                                \
        for (int p = 0; p < 4; ++p)                                      \
            gload16(Bsrc[p] + (kt) * 64, Bs + (p * 64 + lane) * 8);      \
    } while (0)

    const int fr = lane & 15;
    const int off0 = (((lane >> 4))     ^ (lane & 7)) * 8;
    const int off1 = ((4 + (lane >> 4)) ^ (lane & 7)) * 8;

    f32x4 acc[4][2];
#pragma unroll
    for (int m = 0; m < 4; ++m)
#pragma unroll
        for (int n = 0; n < 2; ++n) acc[m][n] = {0.f, 0.f, 0.f, 0.f};

    STAGE2(0);
    const int NKT = Fn / 64;  // 32
    for (int kt = 0; kt < NKT; ++kt) {
        asm volatile("s_waitcnt vmcnt(0)" ::: "memory");
        f16x8 af[4][2], bf[2][2];
#pragma unroll
        for (int m = 0; m < 4; ++m) {
            af[m][0] = *reinterpret_cast<const f16x8*>(As + (m * 16 + fr) * 64 + off0);
            af[m][1] = *reinterpret_cast<const f16x8*>(As + (m * 16 + fr) * 64 + off1);
        }
#pragma unroll
        for (int n = 0; n < 2; ++n) {
            bf[n][0] = *reinterpret_cast<const f16x8*>(Bs + (n * 16 + fr) * 64 + off0);
            bf[n][1] = *reinterpret_cast<const f16x8*>(Bs + (n * 16 + fr) * 64 + off1);
        }
        asm volatile("s_waitcnt lgkmcnt(0)" ::: "memory");
        if (kt + 1 < NKT) STAGE2(kt + 1);
        __builtin_amdgcn_s_setprio(1);
#pragma unroll
        for (int ks = 0; ks < 2; ++ks)
#pragma unroll
            for (int m = 0; m < 4; ++m)
#pragma unroll
                for (int n = 0; n < 2; ++n)
                    acc[m][n] = __builtin_amdgcn_mfma_f32_16x16x32_f16(af[m][ks], bf[n][ks], acc[m][n], 0, 0, 0);
        __builtin_amdgcn_s_setprio(0);
    }
#undef STAGE2

    float b2v[2];
#pragma unroll
    for (int n = 0; n < 2; ++n) b2v[n] = b2[(size_t)e * Dn + nBase + n * 16 + fr];
#pragma unroll
    for (int m = 0; m < 4; ++m) {
#pragma unroll
        for (int j = 0; j < 4; ++j) {
            int i = rowBase + m * 16 + (lane >> 4) * 4 + j;
            if (i < rowEnd) {
                int tok = order[i];
                float s = scale[tok];
#pragma unroll
                for (int n = 0; n < 2; ++n)
                    out[(size_t)tok * Dn + nBase + n * 16 + fr] = (acc[m][n][j] + b2v[n]) * s;
            }
        }
    }
}

extern "C" void kernel_launch(void* const* d_in, const int* in_sizes, int n_in,
                              void* d_out, int out_size, void* d_ws, size_t ws_size,
                              hipStream_t stream) {
    const float* x  = (const float*)d_in[0];
    const float* Ws = (const float*)d_in[1];
    const float* bs = (const float*)d_in[2];
    const float* W1 = (const float*)d_in[3];
    const float* b1 = (const float*)d_in[4];
    const float* W2 = (const float*)d_in[5];
    const float* b2 = (const float*)d_in[6];
    float* out = (float*)d_out;

    char* ws = (char*)d_ws;
    int* nTiles      = (int*)(ws + 0);
    int* tileExpert  = (int*)(ws + 256);
    int* tileBase    = (int*)(ws + 1024);
    int* tileEnd     = (int*)(ws + 2048);
    int* route       = (int*)(ws + 4096);
    float* scale     = (float*)(ws + 4096 + 4 * Tn);
    int* poslocal    = (int*)(ws + 4096 + 8 * Tn);
    int* order       = (int*)(ws + 4096 + 12 * Tn);
    int* blockCounts = (int*)(ws + 4096 + 16 * Tn);
    int* base        = (int*)(ws + 4096 + 16 * Tn + 8192);
    _Float16* x16    = (_Float16*)(ws + (1 << 20));
    _Float16* W1T    = x16 + (size_t)Tn * Dn;
    _Float16* W2T    = W1T + (size_t)En * Dn * Fn;
    _Float16* hbuf   = W2T + (size_t)En * Fn * Dn;

    router_kernel<<<256, 256, 0, stream>>>(x, Ws, bs, x16, route, scale, poslocal, blockCounts);
    plan_kernel<<<1, 256, 0, stream>>>(blockCounts, base, nTiles, tileExpert, tileBase, tileEnd);
    scatter_kernel<<<Tn / 256, 256, 0, stream>>>(route, poslocal, base, order);
    transpose_cvt_kernel<<<4096, 256, 0, stream>>>(W1, W2, W1T, W2T);
    gemm1_kernel<<<dim3(MAXTILES, Fn / 64), 64, 0, stream>>>(
        x16, W1T, b1, order, nTiles, tileExpert, tileBase, tileEnd, hbuf);
    gemm2_kernel<<<dim3(MAXTILES, Dn / 32), 64, 0, stream>>>(
        hbuf, W2T, b2, order, scale, nTiles, tileExpert, tileBase, tileEnd, out);
}

// Round 13
// 112.248 us; speedup vs baseline: 2.8138x; 1.1495x over previous
//
#include <hip/hip_runtime.h>
#include <hip/hip_fp16.h>
#include <cmath>

#define Tn 8192
#define Dn 512
#define Fn 2048
#define En 8

typedef _Float16 f16x8 __attribute__((ext_vector_type(8)));
typedef _Float16 f16x4 __attribute__((ext_vector_type(4)));
typedef float f32x4 __attribute__((ext_vector_type(4)));

#define MAXTILES 136    // ceil(Tn/64) + En = 8*17, divisible by 8 XCDs

__device__ __forceinline__ void gload16(const void* g, void* l) {
    __builtin_amdgcn_global_load_lds(
        (const __attribute__((address_space(1))) unsigned int*)g,
        (__attribute__((address_space(3))) unsigned int*)l, 16, 0, 0);
}

// A&S 7.1.26 rational erf, |eps| <= 1.5e-7
__device__ __forceinline__ float fast_gelu(float v) {
    float z = fabsf(v) * 0.70710678118654752f;
    float t = 1.0f / fmaf(0.3275911f, z, 1.0f);
    float p = t * fmaf(t, fmaf(t, fmaf(t, fmaf(t, 1.061405429f, -1.453152027f),
                                       1.421413741f), -0.284496736f), 0.254829592f);
    float e = __expf(-z * z);
    float erfa = fmaf(-p, e, 1.0f);                 // erf(|z|)
    float phi = 0.5f + copysignf(0.5f * erfa, v);   // 0.5*(1+erf(v/sqrt2))
    return v * phi;
}

// ---------------- fused: router (blocks 0..255) + weight transpose (blocks 256..4351) ----------------
__global__ __launch_bounds__(256) void prep_kernel(
    const float* __restrict__ x, const float* __restrict__ Ws,
    const float* __restrict__ bs, _Float16* __restrict__ x16,
    int* __restrict__ route, float* __restrict__ scale,
    int* __restrict__ poslocal, int* __restrict__ blockCounts,
    const float* __restrict__ W1, const float* __restrict__ W2,
    _Float16* __restrict__ W1T, _Float16* __restrict__ W2T)
{
    __shared__ float tilebuf[64][65];
    __shared__ int hist[8];
    const int tid = threadIdx.x;

    if (blockIdx.x < 256) {
        // ---------- router ----------
        if (tid < 8) hist[tid] = 0;
        __syncthreads();

        const int lane = tid & 63;
        const int w = tid >> 6;
        const int tokBase = blockIdx.x * 32 + w * 8;

        float wreg[8][8];
#pragma unroll
        for (int j = 0; j < 4; ++j) {
            const float4* p = reinterpret_cast<const float4*>(Ws + (4 * lane + j) * En);
            float4 a = p[0], b = p[1];
            wreg[j][0] = a.x; wreg[j][1] = a.y; wreg[j][2] = a.z; wreg[j][3] = a.w;
            wreg[j][4] = b.x; wreg[j][5] = b.y; wreg[j][6] = b.z; wreg[j][7] = b.w;
        }
#pragma unroll
        for (int j = 0; j < 4; ++j) {
            const float4* p = reinterpret_cast<const float4*>(Ws + (256 + 4 * lane + j) * En);
            float4 a = p[0], b = p[1];
            wreg[4 + j][0] = a.x; wreg[4 + j][1] = a.y; wreg[4 + j][2] = a.z; wreg[4 + j][3] = a.w;
            wreg[4 + j][4] = b.x; wreg[4 + j][5] = b.y; wreg[4 + j][6] = b.z; wreg[4 + j][7] = b.w;
        }
        float bsv[8];
#pragma unroll
        for (int e = 0; e < 8; ++e) bsv[e] = bs[e];

        for (int it = 0; it < 8; ++it) {
            int t = tokBase + it;
            const float4* xr = reinterpret_cast<const float4*>(x + (size_t)t * Dn);
            float4 v0 = xr[lane];
            float4 v1 = xr[64 + lane];
            f16x4 h0, h1;
            h0[0] = (_Float16)v0.x; h0[1] = (_Float16)v0.y; h0[2] = (_Float16)v0.z; h0[3] = (_Float16)v0.w;
            h1[0] = (_Float16)v1.x; h1[1] = (_Float16)v1.y; h1[2] = (_Float16)v1.z; h1[3] = (_Float16)v1.w;
            *reinterpret_cast<f16x4*>(x16 + (size_t)t * Dn + 4 * lane) = h0;
            *reinterpret_cast<f16x4*>(x16 + (size_t)t * Dn + 256 + 4 * lane) = h1;

            float xv[8] = {v0.x, v0.y, v0.z, v0.w, v1.x, v1.y, v1.z, v1.w};
            float part[8];
#pragma unroll
            for (int e = 0; e < 8; ++e) part[e] = 0.f;
#pragma unroll
            for (int j = 0; j < 8; ++j)
#pragma unroll
                for (int e = 0; e < 8; ++e) part[e] = fmaf(xv[j], wreg[j][e], part[e]);
#pragma unroll
            for (int s = 32; s > 0; s >>= 1) {
#pragma unroll
                for (int e = 0; e < 8; ++e) part[e] += __shfl_xor(part[e], s);
            }
            if (lane == 0) {
                float lg[8];
                lg[0] = part[0] + bsv[0];
                float m = lg[0]; int am = 0;
#pragma unroll
                for (int e = 1; e < 8; ++e) {
                    lg[e] = part[e] + bsv[e];
                    if (lg[e] > m) { m = lg[e]; am = e; }   // first-max tie rule
                }
                float sum = 0.f;
#pragma unroll
                for (int e = 0; e < 8; ++e) sum += expf(lg[e] - m);
                route[t] = am;
                scale[t] = 1.0f / sum;                 // top-1 softmax prob
                poslocal[t] = atomicAdd(&hist[am], 1); // LDS atomic: local rank
            }
        }
        __syncthreads();
        if (tid < 8) blockCounts[blockIdx.x * 8 + tid] = hist[tid];
        return;
    }

    // ---------- weight transpose + fp32->fp16 ----------
    int bx = blockIdx.x - 256;
    const float* in; _Float16* outp; int R, C, tR, tC;
    if (bx < 2048) {            // W1[e]: [D][F] -> W1T[e]: [F][D]
        int e = bx >> 8, t = bx & 255;
        R = Dn; C = Fn; tR = t >> 5; tC = t & 31;
        in = W1 + (size_t)e * Dn * Fn;
        outp = W1T + (size_t)e * Dn * Fn;
    } else {                    // W2[e]: [F][D] -> W2T[e]: [D][F]
        int b2 = bx - 2048;
        int e = b2 >> 8, t = b2 & 255;
        R = Fn; C = Dn; tR = t >> 3; tC = t & 7;
        in = W2 + (size_t)e * Fn * Dn;
        outp = W2T + (size_t)e * Fn * Dn;
    }
    int r0 = tR * 64, c0 = tC * 64;
    int row = tid >> 2, cq = tid & 3;
#pragma unroll
    for (int i = 0; i < 4; ++i) {
        float4 v = *reinterpret_cast<const float4*>(in + (size_t)(r0 + row) * C + c0 + cq * 16 + i * 4);
        tilebuf[row][cq * 16 + i * 4 + 0] = v.x;
        tilebuf[row][cq * 16 + i * 4 + 1] = v.y;
        tilebuf[row][cq * 16 + i * 4 + 2] = v.z;
        tilebuf[row][cq * 16 + i * 4 + 3] = v.w;
    }
    __syncthreads();
    int col = tid >> 2, rq = tid & 3;
    f16x8 o0, o1;
#pragma unroll
    for (int i = 0; i < 8; ++i) o0[i] = (_Float16)tilebuf[rq * 16 + i][col];
#pragma unroll
    for (int i = 0; i < 8; ++i) o1[i] = (_Float16)tilebuf[rq * 16 + 8 + i][col];
    size_t base = (size_t)(c0 + col) * R + r0 + rq * 16;
    *reinterpret_cast<f16x8*>(outp + base) = o0;
    *reinterpret_cast<f16x8*>(outp + base + 8) = o1;
}

// ---------------- plan: prefix sums (no atomics) + tile table ----------------
__global__ __launch_bounds__(256) void plan_kernel(
    const int* __restrict__ blockCounts,   // [256][8]
    int* __restrict__ base,                // [256][8] out
    int* __restrict__ nTiles, int* __restrict__ tileExpert,
    int* __restrict__ tileBase, int* __restrict__ tileEnd)
{
    __shared__ int cnt[256 * 8];
    __shared__ int groupSum[32 * 8];
    __shared__ int groupBase[32 * 8];
    __shared__ int totals[8];
    __shared__ int offsets_s[8];
    const int tid = threadIdx.x;
    for (int i = tid; i < 2048; i += 256) cnt[i] = blockCounts[i];
    __syncthreads();
    const int e = tid & 7, g = tid >> 3;
    {
        int s = 0;
#pragma unroll
        for (int b = g * 8; b < g * 8 + 8; ++b) s += cnt[b * 8 + e];
        groupSum[g * 8 + e] = s;
    }
    __syncthreads();
    if (tid < 8) {
        int run = 0;
        for (int gg = 0; gg < 32; ++gg) {
            groupBase[gg * 8 + tid] = run;
            run += groupSum[gg * 8 + tid];
        }
        totals[tid] = run;
    }
    __syncthreads();
    if (tid == 0) {
        int off = 0, nt = 0;
        for (int ee = 0; ee < En; ++ee) {
            offsets_s[ee] = off;
            int c = totals[ee];
            int tiles = (c + 63) / 64;
            for (int r = 0; r < tiles; ++r) {
                tileExpert[nt] = ee;
                tileBase[nt] = off + r * 64;
                tileEnd[nt] = off + c;
                ++nt;
            }
            off += c;
        }
        *nTiles = nt;
    }
    __syncthreads();
    {
        int run = offsets_s[e] + groupBase[g * 8 + e];
#pragma unroll
        for (int b = g * 8; b < g * 8 + 8; ++b) {
            base[b * 8 + e] = run;
            run += cnt[b * 8 + e];
        }
    }
}

// ---------------- scatter: pure writes, no atomics ----------------
__global__ __launch_bounds__(256) void scatter_kernel(
    const int* __restrict__ route, const int* __restrict__ poslocal,
    const int* __restrict__ base, int* __restrict__ order)
{
    int t = blockIdx.x * 256 + threadIdx.x;
    if (t >= Tn) return;
    int e = route[t];
    int rb = t >> 5;
    order[base[rb * 8 + e] + poslocal[t]] = t;
}

// ---------------- GEMM1: h = gelu(Xg @ W1 + b1) ----------------
// R7 structure + XCD swizzle + fast_gelu. ONE WAVE per block, 64x64 tile, BK=64,
// single LDS buffer, gload_lds + XOR-8 swizzle (0 conflicts).
__global__ __launch_bounds__(64) void gemm1_kernel(
    const _Float16* __restrict__ x16, const _Float16* __restrict__ W1T,
    const float* __restrict__ b1, const int* __restrict__ order,
    const int* __restrict__ nTiles, const int* __restrict__ tileExpert,
    const int* __restrict__ tileBase, const int* __restrict__ tileEnd,
    _Float16* __restrict__ hbuf)
{
    __shared__ _Float16 As[64 * 64];   // 8 KB
    __shared__ _Float16 Bs[64 * 64];   // 8 KB
    const int bx = blockIdx.x;
    const int bt = (bx & 7) * 17 + (bx >> 3);   // XCD-aware: 136 = 8*17
    if (bt >= *nTiles) return;
    const int e = tileExpert[bt], rowBase = tileBase[bt], rowEnd = tileEnd[bt];
    const int nBase = blockIdx.y * 64;
    const int lane = threadIdx.x;

    const int swc = ((lane & 7) ^ (lane >> 3)) * 8;
    const _Float16* Asrc[8];
    const _Float16* Bsrc[8];
#pragma unroll
    for (int p = 0; p < 8; ++p) {
        int r = p * 8 + (lane >> 3);
        int tok = order[min(rowBase + r, Tn - 1)];
        Asrc[p] = x16 + (size_t)tok * Dn + swc;
        Bsrc[p] = W1T + (size_t)e * Dn * Fn + (size_t)(nBase + r) * Dn + swc;
    }

#define STAGE1(kt) do {                                                  \
        _Pragma("unroll")                                                \
        for (int p = 0; p < 8; ++p) {                                    \
            gload16(Asrc[p] + (kt) * 64, As + (p * 64 + lane) * 8);      \
            gload16(Bsrc[p] + (kt) * 64, Bs + (p * 64 + lane) * 8);      \
        }                                                                \
    } while (0)

    const int fr = lane & 15;
    const int off0 = (((lane >> 4))     ^ (lane & 7)) * 8;
    const int off1 = ((4 + (lane >> 4)) ^ (lane & 7)) * 8;

    f32x4 acc[4][4];
#pragma unroll
    for (int m = 0; m < 4; ++m)
#pragma unroll
        for (int n = 0; n < 4; ++n) acc[m][n] = {0.f, 0.f, 0.f, 0.f};

    STAGE1(0);
    const int NKT = Dn / 64;  // 8
    for (int kt = 0; kt < NKT; ++kt) {
        asm volatile("s_waitcnt vmcnt(0)" ::: "memory");
        f16x8 af[4][2], bf[4][2];
#pragma unroll
        for (int m = 0; m < 4; ++m) {
            af[m][0] = *reinterpret_cast<const f16x8*>(As + (m * 16 + fr) * 64 + off0);
            af[m][1] = *reinterpret_cast<const f16x8*>(As + (m * 16 + fr) * 64 + off1);
        }
#pragma unroll
        for (int n = 0; n < 4; ++n) {
            bf[n][0] = *reinterpret_cast<const f16x8*>(Bs + (n * 16 + fr) * 64 + off0);
            bf[n][1] = *reinterpret_cast<const f16x8*>(Bs + (n * 16 + fr) * 64 + off1);
        }
        asm volatile("s_waitcnt lgkmcnt(0)" ::: "memory");
        if (kt + 1 < NKT) STAGE1(kt + 1);
        __builtin_amdgcn_s_setprio(1);
#pragma unroll
        for (int ks = 0; ks < 2; ++ks)
#pragma unroll
            for (int m = 0; m < 4; ++m)
#pragma unroll
                for (int n = 0; n < 4; ++n)
                    acc[m][n] = __builtin_amdgcn_mfma_f32_16x16x32_f16(af[m][ks], bf[n][ks], acc[m][n], 0, 0, 0);
        __builtin_amdgcn_s_setprio(0);
    }
#undef STAGE1

    float b1v[4];
#pragma unroll
    for (int n = 0; n < 4; ++n) b1v[n] = b1[(size_t)e * Fn + nBase + n * 16 + fr];
#pragma unroll
    for (int m = 0; m < 4; ++m) {
#pragma unroll
        for (int j = 0; j < 4; ++j) {
            int i = rowBase + m * 16 + (lane >> 4) * 4 + j;
            if (i < rowEnd) {
#pragma unroll
                for (int n = 0; n < 4; ++n) {
                    float g = fast_gelu(acc[m][n][j] + b1v[n]);
                    hbuf[(size_t)i * Fn + nBase + n * 16 + fr] = (_Float16)g;
                }
            }
        }
    }
}

// ---------------- GEMM2: out = (h @ W2 + b2) * prob ----------------
// Same structure as gemm1: ONE WAVE per block, 64x64 tile, K=2048, BK=64,
// 16 KB LDS, XCD swizzle. Halves A re-reads vs the old 64x32 tile.
__global__ __launch_bounds__(64) void gemm2_kernel(
    const _Float16* __restrict__ hbuf, const _Float16* __restrict__ W2T,
    const float* __restrict__ b2, const int* __restrict__ order,
    const float* __restrict__ scale,
    const int* __restrict__ nTiles, const int* __restrict__ tileExpert,
    const int* __restrict__ tileBase, const int* __restrict__ tileEnd,
    float* __restrict__ out)
{
    __shared__ _Float16 As[64 * 64];   // 8 KB
    __shared__ _Float16 Bs[64 * 64];   // 8 KB
    const int bx = blockIdx.x;
    const int bt = (bx & 7) * 17 + (bx >> 3);
    if (bt >= *nTiles) return;
    const int e = tileExpert[bt], rowBase = tileBase[bt], rowEnd = tileEnd[bt];
    const int nBase = blockIdx.y * 64;
    const int lane = threadIdx.x;

    const int swc = ((lane & 7) ^ (lane >> 3)) * 8;
    const _Float16* Asrc[8];
    const _Float16* Bsrc[8];
#pragma unroll
    for (int p = 0; p < 8; ++p) {
        int r = p * 8 + (lane >> 3);
        Asrc[p] = hbuf + (size_t)min(rowBase + r, Tn - 1) * Fn + swc;
        Bsrc[p] = W2T + (size_t)e * Fn * Dn + (size_t)(nBase + r) * Fn + swc;
    }

#define STAGE2(kt) do {                                                  \
        _Pragma("unroll")                                                \
        for (int p = 0; p < 8; ++p) {                                    \
            gload16(Asrc[p] + (kt) * 64, As + (p * 64 + lane) * 8);      \
            gload16(Bsrc[p] + (kt) * 64, Bs + (p * 64 + lane) * 8);      \
        }                                                                \
    } while (0)

    const int fr = lane & 15;
    const int off0 = (((lane >> 4))     ^ (lane & 7)) * 8;
    const int off1 = ((4 + (lane >> 4)) ^ (lane & 7)) * 8;

    f32x4 acc[4][4];
#pragma unroll
    for (int m = 0; m < 4; ++m)
#pragma unroll
        for (int n = 0; n < 4; ++n) acc[m][n] = {0.f, 0.f, 0.f, 0.f};

    STAGE2(0);
    const int NKT = Fn / 64;  // 32
    for (int kt = 0; kt < NKT; ++kt) {
        asm volatile("s_waitcnt vmcnt(0)" ::: "memory");
        f16x8 af[4][2], bf[4][2];
#pragma unroll
        for (int m = 0; m < 4; ++m) {
            af[m][0] = *reinterpret_cast<const f16x8*>(As + (m * 16 + fr) * 64 + off0);
            af[m][1] = *reinterpret_cast<const f16x8*>(As + (m * 16 + fr) * 64 + off1);
        }
#pragma unroll
        for (int n = 0; n < 4; ++n) {
            bf[n][0] = *reinterpret_cast<const f16x8*>(Bs + (n * 16 + fr) * 64 + off0);
            bf[n][1] = *reinterpret_cast<const f16x8*>(Bs + (n * 16 + fr) * 64 + off1);
        }
        asm volatile("s_waitcnt lgkmcnt(0)" ::: "memory");
        if (kt + 1 < NKT) STAGE2(kt + 1);
        __builtin_amdgcn_s_setprio(1);
#pragma unroll
        for (int ks = 0; ks < 2; ++ks)
#pragma unroll
            for (int m = 0; m < 4; ++m)
#pragma unroll
                for (int n = 0; n < 4; ++n)
                    acc[m][n] = __builtin_amdgcn_mfma_f32_16x16x32_f16(af[m][ks], bf[n][ks], acc[m][n], 0, 0, 0);
        __builtin_amdgcn_s_setprio(0);
    }
#undef STAGE2

    float b2v[4];
#pragma unroll
    for (int n = 0; n < 4; ++n) b2v[n] = b2[(size_t)e * Dn + nBase + n * 16 + fr];
#pragma unroll
    for (int m = 0; m < 4; ++m) {
#pragma unroll
        for (int j = 0; j < 4; ++j) {
            int i = rowBase + m * 16 + (lane >> 4) * 4 + j;
            if (i < rowEnd) {
                int tok = order[i];
                float s = scale[tok];
#pragma unroll
                for (int n = 0; n < 4; ++n)
                    out[(size_t)tok * Dn + nBase + n * 16 + fr] = (acc[m][n][j] + b2v[n]) * s;
            }
        }
    }
}

extern "C" void kernel_launch(void* const* d_in, const int* in_sizes, int n_in,
                              void* d_out, int out_size, void* d_ws, size_t ws_size,
                              hipStream_t stream) {
    const float* x  = (const float*)d_in[0];
    const float* Ws = (const float*)d_in[1];
    const float* bs = (const float*)d_in[2];
    const float* W1 = (const float*)d_in[3];
    const float* b1 = (const float*)d_in[4];
    const float* W2 = (const float*)d_in[5];
    const float* b2 = (const float*)d_in[6];
    float* out = (float*)d_out;

    char* ws = (char*)d_ws;
    int* nTiles      = (int*)(ws + 0);
    int* tileExpert  = (int*)(ws + 256);
    int* tileBase    = (int*)(ws + 1024);
    int* tileEnd     = (int*)(ws + 2048);
    int* route       = (int*)(ws + 4096);
    float* scale     = (float*)(ws + 4096 + 4 * Tn);
    int* poslocal    = (int*)(ws + 4096 + 8 * Tn);
    int* order       = (int*)(ws + 4096 + 12 * Tn);
    int* blockCounts = (int*)(ws + 4096 + 16 * Tn);
    int* base        = (int*)(ws + 4096 + 16 * Tn + 8192);
    _Float16* x16    = (_Float16*)(ws + (1 << 20));
    _Float16* W1T    = x16 + (size_t)Tn * Dn;
    _Float16* W2T    = W1T + (size_t)En * Dn * Fn;
    _Float16* hbuf   = W2T + (size_t)En * Fn * Dn;

    prep_kernel<<<256 + 4096, 256, 0, stream>>>(x, Ws, bs, x16, route, scale, poslocal,
                                                blockCounts, W1, W2, W1T, W2T);
    plan_kernel<<<1, 256, 0, stream>>>(blockCounts, base, nTiles, tileExpert, tileBase, tileEnd);
    scatter_kernel<<<Tn / 256, 256, 0, stream>>>(route, poslocal, base, order);
    gemm1_kernel<<<dim3(MAXTILES, Fn / 64), 64, 0, stream>>>(
        x16, W1T, b1, order, nTiles, tileExpert, tileBase, tileEnd, hbuf);
    gemm2_kernel<<<dim3(MAXTILES, Dn / 64), 64, 0, stream>>>(
        hbuf, W2T, b2, order, scale, nTiles, tileExpert, tileBase, tileEnd, out);
}